// Round 27
// baseline (605.301 us; speedup 1.0000x reference)
//
#include <hip/hip_runtime.h>
#include <hip/hip_bf16.h>
#include <math.h>

#define N_NODES 50000
#define N_EDGES 500000
#define DIM     128
#define NLAYER  4
#define NEFEAT  7

static constexpr float LN_EPS    = 1e-5f;
static constexpr float ATT_SCALE = 0.17677669529663687f;  // 1/sqrt(32)

typedef short s16x8 __attribute__((ext_vector_type(8)));   // 8 bf16 (4 VGPR) MFMA A/B frag
typedef float f32x4 __attribute__((ext_vector_type(4)));   // MFMA C/D frag

static __device__ __forceinline__ float leaky(float x){ return x >= 0.f ? x : 0.01f*x; }

static __device__ __forceinline__ unsigned short f2bf(float f){
    __hip_bfloat16 b = __float2bfloat16(f);
    return *reinterpret_cast<unsigned short*>(&b);
}
static __device__ __forceinline__ float bflo(unsigned int u){ return __uint_as_float(u << 16); }
static __device__ __forceinline__ float bfhi(unsigned int u){ return __uint_as_float(u & 0xFFFF0000u); }

// 16-lane (per-head) sum via DPP row rotations: pure VALU, no LDS pipe.
template<int CTRL>
static __device__ __forceinline__ float dpp_ror_add(float x){
    int r = __builtin_amdgcn_update_dpp(0, __float_as_int(x), CTRL, 0xf, 0xf, true);
    return x + __int_as_float(r);
}
static __device__ __forceinline__ float sum16(float x){
    x = dpp_ror_add<0x128>(x);   // row_ror:8
    x = dpp_ror_add<0x124>(x);   // row_ror:4
    x = dpp_ror_add<0x122>(x);   // row_ror:2
    x = dpp_ror_add<0x121>(x);   // row_ror:1
    return x;
}
static __device__ __forceinline__ float sum64(float x){
    x = sum16(x);
    x += __shfl_xor(x, 16);
    x += __shfl_xor(x, 32);
    return x;
}

// ---------------- init h = node_table[0] broadcast (fp32 + bf16 shadow) ----------------
__global__ void init_h_kernel(const float* __restrict__ node_table,
                              float* __restrict__ h, unsigned short* __restrict__ hb){
    int i = blockIdx.x*blockDim.x + threadIdx.x;
    if (i < N_NODES*DIM){
        float v = node_table[i & (DIM-1)];
        h[i]  = v;
        hb[i] = f2bf(v);
    }
}

// ---------------- CSR build ----------------
__global__ void zero2_kernel(int* __restrict__ a, int* __restrict__ b){
    int i = blockIdx.x*blockDim.x + threadIdx.x;
    if (i < N_NODES){ a[i] = 0; b[i] = 0; }
}

__global__ void count_kernel(const int* __restrict__ dst, int* __restrict__ cnt){
    int e = blockIdx.x*blockDim.x + threadIdx.x;
    if (e < N_EDGES) atomicAdd(&cnt[dst[e]], 1);
}

// parallel scan: per-block exclusive scan + block sums
__global__ void scan1_kernel(const int* __restrict__ cnt, int* __restrict__ rowptr,
                             int* __restrict__ bsum){
    __shared__ int wsum[16];
    int t = threadIdx.x;
    int i = blockIdx.x*1024 + t;
    int lane = t & 63, wid = t >> 6;
    int v = (i < N_NODES) ? cnt[i] : 0;
    int s = v;
    #pragma unroll
    for (int off = 1; off < 64; off <<= 1){
        int tt = __shfl_up(s, off);
        if (lane >= off) s += tt;
    }
    if (lane == 63) wsum[wid] = s;
    __syncthreads();
    if (wid == 0 && lane < 16){
        int x = wsum[lane];
        #pragma unroll
        for (int off = 1; off < 16; off <<= 1){
            int tt = __shfl_up(x, off);
            if (lane >= off) x += tt;
        }
        wsum[lane] = x;
    }
    __syncthreads();
    int wpre = (wid == 0) ? 0 : wsum[wid-1];
    if (i < N_NODES) rowptr[i] = wpre + s - v;      // exclusive within block
    if (t == 1023) bsum[blockIdx.x] = wpre + s;     // block total
}

__global__ void scan2_kernel(const int* __restrict__ bsum, int* __restrict__ boff,
                             int nb, int* __restrict__ totalp){
    int t = threadIdx.x;   // 64 threads
    int v = (t < nb) ? bsum[t] : 0;
    int s = v;
    #pragma unroll
    for (int off = 1; off < 64; off <<= 1){
        int tt = __shfl_up(s, off);
        if (t >= off) s += tt;
    }
    if (t < nb) boff[t] = s - v;
    if (t == 63) *totalp = s;
}

__global__ void scan3_kernel(int* __restrict__ rowptr, const int* __restrict__ boff){
    int i = blockIdx.x*1024 + threadIdx.x;
    if (i < N_NODES) rowptr[i] += boff[blockIdx.x];
}

__global__ void scatter_kernel(const int* __restrict__ src, const int* __restrict__ dst,
                               const float* __restrict__ edge_attr,
                               const int* __restrict__ rowptr, int* __restrict__ fill,
                               int* __restrict__ srcs, unsigned int* __restrict__ eab){
    int e = blockIdx.x*blockDim.x + threadIdx.x;
    if (e >= N_EDGES) return;
    int d   = dst[e];
    int pos = rowptr[d] + atomicAdd(&fill[d], 1);
    srcs[pos] = src[e];
    const float* a = edge_attr + (size_t)e*NEFEAT;
    uint4 u;
    u.x = (unsigned int)f2bf(a[0]) | ((unsigned int)f2bf(a[1]) << 16);
    u.y = (unsigned int)f2bf(a[2]) | ((unsigned int)f2bf(a[3]) << 16);
    u.z = (unsigned int)f2bf(a[4]) | ((unsigned int)f2bf(a[5]) << 16);
    u.w = (unsigned int)f2bf(a[6]) | (0x3F80u << 16);   // bias slot = 1.0
    *(uint4*)(eab + (size_t)pos*4) = u;
}

// ---------------- Weff[l] = [Wee@We_l ; bee@We_l + be_l]  (8 x 128), all layers ----------
__global__ void weff_all_kernel(const float* __restrict__ Wee, const float* __restrict__ bee,
                                const float* __restrict__ We, const float* __restrict__ be,
                                float* __restrict__ weff){
    int l = blockIdx.x;
    int d = threadIdx.x;  // 128 threads
    const float* We_l = We + (size_t)l*DIM*DIM;
    float* out = weff + (size_t)l*8*DIM;
    for (int c = 0; c < NEFEAT; ++c){
        float s = 0.f;
        for (int t = 0; t < DIM; ++t) s += Wee[c*DIM + t] * We_l[t*DIM + d];
        out[c*DIM + d] = s;
    }
    float s = 0.f;
    for (int t = 0; t < DIM; ++t) s += bee[t] * We_l[t*DIM + d];
    out[7*DIM + d] = s + be[l*DIM + d];
}

// ---------------- weight prep: bf16 transposed copies ----------------
__global__ void prepw_kernel(const float* __restrict__ Wq, const float* __restrict__ Wk,
                             const float* __restrict__ Wv, const float* __restrict__ Ws,
                             const float* __restrict__ W1, const float* __restrict__ W2,
                             unsigned short* __restrict__ wqkvsT,
                             unsigned short* __restrict__ w1T,
                             unsigned short* __restrict__ w2T){
    int tid = blockIdx.x*blockDim.x + threadIdx.x;
    if (tid >= NLAYER*131072) return;
    int l = tid >> 17;
    int r = tid & 131071;
    if (r < 65536){
        int n = r >> 7, k = r & 127;
        int p = n >> 7, nn = n & 127;
        const float* W = (p==0)?Wq:(p==1)?Wk:(p==2)?Wv:Ws;
        float val = W[(size_t)l*DIM*DIM + (size_t)k*DIM + nn];
        wqkvsT[(size_t)l*65536 + (size_t)n*128 + k] = f2bf(val);
    } else if (r < 98304){
        int r2 = r - 65536;
        int n = r2 >> 7, k = r2 & 127;
        float val = W1[(size_t)l*32768 + (size_t)k*256 + n];
        w1T[(size_t)l*32768 + (size_t)n*128 + k] = f2bf(val);
    } else {
        int r2 = r - 98304;
        int n = r2 >> 8, k = r2 & 255;
        float val = W2[(size_t)l*32768 + (size_t)k*128 + n];
        w2T[(size_t)l*32768 + (size_t)n*256 + k] = f2bf(val);
    }
}

// ---------------- standalone QKVS (layer 0 only): 32-row tiles ----------------
__global__ __launch_bounds__(256) void qkvs_mfma_kernel(
    const unsigned short* __restrict__ hb, const unsigned short* __restrict__ wT,
    const float* __restrict__ bq, const float* __restrict__ bk,
    const float* __restrict__ bv, const float* __restrict__ bs,
    unsigned int* __restrict__ qs, unsigned int* __restrict__ kv)
{
    __shared__ char sA[32*256];   // [32][128] bf16, XOR-swizzled (8 KB)
    int row0 = blockIdx.x*32;
    for (int idx = threadIdx.x; idx < 512; idx += 256){
        int row = idx >> 4, k16 = idx & 15;
        int byte = row*256 + k16*16;  byte ^= (row & 7) << 4;
        s16x8 val = {0,0,0,0,0,0,0,0};
        int grow = row0 + row;
        if (grow < N_NODES) val = *(const s16x8*)(hb + (size_t)grow*128 + k16*8);
        *(s16x8*)(sA + byte) = val;
    }
    __syncthreads();

    int w = threadIdx.x >> 6, l = threadIdx.x & 63;
    int y = blockIdx.y;
    int pb0 = y ? 128 : 0;
    int pb1 = y ? 256 : 384;

    f32x4 acc[2][4];
    #pragma unroll
    for (int rf=0;rf<2;++rf)
        #pragma unroll
        for (int cf=0;cf<4;++cf) acc[rf][cf] = (f32x4){0.f,0.f,0.f,0.f};

    s16x8 af[2][2], bf[2][4];
    #pragma unroll
    for (int rf=0;rf<2;++rf){
        int row = rf*16 + (l & 15);
        int byte = row*256 + (l >> 4)*16;  byte ^= (row & 7) << 4;
        af[0][rf] = *(const s16x8*)(sA + byte);
    }
    #pragma unroll
    for (int cf=0;cf<4;++cf){
        int nrow = ((cf < 2) ? pb0 : pb1) + (w<<5) + ((cf&1)<<4) + (l & 15);
        bf[0][cf] = *(const s16x8*)(wT + (size_t)nrow*128 + (l >> 4)*8);
    }
    #pragma unroll
    for (int kb = 0; kb < 4; ++kb){
        int cur = kb & 1, nxt = cur ^ 1;
        if (kb < 3){
            #pragma unroll
            for (int rf=0;rf<2;++rf){
                int row = rf*16 + (l & 15);
                int byte = row*256 + (kb+1)*64 + (l >> 4)*16;  byte ^= (row & 7) << 4;
                af[nxt][rf] = *(const s16x8*)(sA + byte);
            }
            #pragma unroll
            for (int cf=0;cf<4;++cf){
                int nrow = ((cf < 2) ? pb0 : pb1) + (w<<5) + ((cf&1)<<4) + (l & 15);
                bf[nxt][cf] = *(const s16x8*)(wT + (size_t)nrow*128 + (kb+1)*32 + (l >> 4)*8);
            }
        }
        #pragma unroll
        for (int rf=0;rf<2;++rf)
            #pragma unroll
            for (int cf=0;cf<4;++cf)
                acc[rf][cf] = __builtin_amdgcn_mfma_f32_16x16x32_bf16(af[cur][rf], bf[cur][cf], acc[rf][cf], 0, 0, 0);
    }

    const float* biasLo = y ? bk : bq;
    const float* biasHi = y ? bv : bs;
    unsigned int* outp  = y ? kv : qs;
    #pragma unroll
    for (int cp = 0; cp < 2; ++cp){
        int col = (w<<5) + (cp<<4) + (l & 15);
        float blo = biasLo[col], bhi = biasHi[col];
        #pragma unroll
        for (int rf=0;rf<2;++rf){
            #pragma unroll
            for (int r=0;r<4;++r){
                int row = row0 + rf*16 + ((l >> 4) << 2) + r;
                if (row < N_NODES){
                    float lo = acc[rf][cp][r]   + blo;
                    float hi = acc[rf][cp+2][r] + bhi;
                    outp[(size_t)row*128 + col] =
                        (unsigned int)f2bf(lo) | ((unsigned int)f2bf(hi) << 16);
                }
            }
        }
    }
}

// ---------------- attention + skip + LN1 fused: one wave per destination node -----------
// Augmented-dot + DPP reductions; unroll-4 edge loop for 4 gathers in flight.
__global__ __launch_bounds__(256) void attn_kernel(
    const unsigned int* __restrict__ qs, const unsigned int* __restrict__ kv,
    const float* __restrict__ weff_l, const int* __restrict__ rowptr,
    const int* __restrict__ srcs, const unsigned int* __restrict__ eab,
    const float* __restrict__ h,
    const float* __restrict__ n1g, const float* __restrict__ n1b,
    unsigned short* __restrict__ x1b)
{
    __shared__ float wf[8][DIM];           // 4 KB
    __shared__ float els[4][64][9];        // per-wave 64-edge feature tile (+pad)
    for (int i = threadIdx.x; i < 8*DIM; i += 256) ((float*)wf)[i] = weff_l[i];
    __syncthreads();
    int wv = threadIdx.x >> 6, lane = threadIdx.x & 63;
    int n = blockIdx.x*4 + wv;
    if (n >= N_NODES) return;
    float (*el)[9] = els[wv];

    int d0 = lane*2;
    int fi = lane & 15;
    int fc = fi & 7;

    uint2 qsb = *(const uint2*)(qs + (size_t)n*DIM + d0);
    float q0 = bflo(qsb.x)*ATT_SCALE, q1 = bflo(qsb.y)*ATT_SCALE;
    float s0 = bfhi(qsb.x), s1 = bfhi(qsb.y);

    float qe[8];
    #pragma unroll
    for (int c = 0; c < 8; ++c){
        float2 wc = *(const float2*)&wf[c][d0];
        qe[c] = sum16(q0*wc.x + q1*wc.y);
    }
    float qaug = qe[0];
    qaug = (fc==1) ? qe[1] : qaug;
    qaug = (fc==2) ? qe[2] : qaug;
    qaug = (fc==3) ? qe[3] : qaug;
    qaug = (fc==4) ? qe[4] : qaug;
    qaug = (fc==5) ? qe[5] : qaug;
    qaug = (fc==6) ? qe[6] : qaug;
    qaug = (fc==7) ? qe[7] : qaug;
    qaug = (fi < 8) ? qaug : 0.f;

    int beg = rowptr[n], deg = rowptr[n+1] - beg;
    float a0 = 0.f, a1 = 0.f, peaL = 0.f;

    for (int cb = 0; cb < deg; cb += 64){
        int base = beg + cb;
        int cdeg = deg - cb; if (cdeg > 64) cdeg = 64;
        int srcv = 0;
        uint4 eu = {0u,0u,0u,0u};
        if (cb + lane < deg){
            srcv = srcs[base + lane];
            eu = *(const uint4*)(eab + ((size_t)(base + lane) << 2));
        }
        asm volatile("s_waitcnt lgkmcnt(0)" ::: "memory");
        __builtin_amdgcn_sched_barrier(0);
        {
            float* row = el[lane];
            row[0] = bflo(eu.x); row[1] = bfhi(eu.x);
            row[2] = bflo(eu.y); row[3] = bfhi(eu.y);
            row[4] = bflo(eu.z); row[5] = bfhi(eu.z);
            row[6] = bflo(eu.w); row[7] = bfhi(eu.w);   // bias slot = 1.0
        }
        asm volatile("s_waitcnt lgkmcnt(0)" ::: "memory");
        __builtin_amdgcn_sched_barrier(0);

        int j = 0;
        for (; j + 3 < cdeg; j += 4){
            int svA = __builtin_amdgcn_readlane(srcv, j);
            int svB = __builtin_amdgcn_readlane(srcv, j+1);
            int svC = __builtin_amdgcn_readlane(srcv, j+2);
            int svD = __builtin_amdgcn_readlane(srcv, j+3);
            uint2 kvA = *(const uint2*)(kv + (size_t)svA*DIM + d0);
            uint2 kvB = *(const uint2*)(kv + (size_t)svB*DIM + d0);
            uint2 kvC = *(const uint2*)(kv + (size_t)svC*DIM + d0);
            uint2 kvD = *(const uint2*)(kv + (size_t)svD*DIM + d0);
            float eaA = el[j][fc];
            float eaB = el[j+1][fc];
            float eaC = el[j+2][fc];
            float eaD = el[j+3][fc];
            float pA = sum16(q0*bflo(kvA.x) + q1*bflo(kvA.y) + qaug*eaA);
            float pB = sum16(q0*bflo(kvB.x) + q1*bflo(kvB.y) + qaug*eaB);
            float pC = sum16(q0*bflo(kvC.x) + q1*bflo(kvC.y) + qaug*eaC);
            float pD = sum16(q0*bflo(kvD.x) + q1*bflo(kvD.y) + qaug*eaD);
            float ppA = __expf(pA);
            float ppB = __expf(pB);
            float ppC = __expf(pC);
            float ppD = __expf(pD);
            a0   += ppA*bfhi(kvA.x) + ppB*bfhi(kvB.x) + ppC*bfhi(kvC.x) + ppD*bfhi(kvD.x);
            a1   += ppA*bfhi(kvA.y) + ppB*bfhi(kvB.y) + ppC*bfhi(kvC.y) + ppD*bfhi(kvD.y);
            peaL += ppA*eaA + ppB*eaB + ppC*eaC + ppD*eaD;
        }
        for (; j < cdeg; ++j){
            int sv = __builtin_amdgcn_readlane(srcv, j);
            uint2 kva = *(const uint2*)(kv + (size_t)sv*DIM + d0);
            float ea = el[j][fc];
            float p = sum16(q0*bflo(kva.x) + q1*bflo(kva.y) + qaug*ea);
            float pp = __expf(p);
            a0   += pp*bfhi(kva.x);
            a1   += pp*bfhi(kva.y);
            peaL += pp*ea;
        }
    }

    int hb_ = lane & 48;
    float pc0 = __shfl(peaL, hb_ + 0);
    float pc1 = __shfl(peaL, hb_ + 1);
    float pc2 = __shfl(peaL, hb_ + 2);
    float pc3 = __shfl(peaL, hb_ + 3);
    float pc4 = __shfl(peaL, hb_ + 4);
    float pc5 = __shfl(peaL, hb_ + 5);
    float pc6 = __shfl(peaL, hb_ + 6);
    float den = __shfl(peaL, hb_ + 7);    // ea7 == 1 -> pea7 == sum(exp)

    float inv = (den > 0.f) ? 1.f/den : 0.f;
    float ev0, ev1;
    {
        float2 w0 = *(const float2*)&wf[0][d0];
        float2 w1c = *(const float2*)&wf[1][d0];
        float2 w2c = *(const float2*)&wf[2][d0];
        float2 w3c = *(const float2*)&wf[3][d0];
        float2 w4c = *(const float2*)&wf[4][d0];
        float2 w5c = *(const float2*)&wf[5][d0];
        float2 w6c = *(const float2*)&wf[6][d0];
        float2 w7c = *(const float2*)&wf[7][d0];
        ev0 = pc0*w0.x + pc1*w1c.x + pc2*w2c.x + pc3*w3c.x
            + pc4*w4c.x + pc5*w5c.x + pc6*w6c.x + den*w7c.x;
        ev1 = pc0*w0.y + pc1*w1c.y + pc2*w2c.y + pc3*w3c.y
            + pc4*w4c.y + pc5*w5c.y + pc6*w6c.y + den*w7c.y;
    }

    float2 hv = *(const float2*)(h + (size_t)n*DIM + d0);
    float t0 = hv.x + (a0 + ev0)*inv + s0;
    float t1 = hv.y + (a1 + ev1)*inv + s1;
    float sum = sum64(t0 + t1);
    float ss  = sum64(t0*t0 + t1*t1);
    float mu = sum * (1.f/DIM);
    float rstd = rsqrtf(ss*(1.f/DIM) - mu*mu + LN_EPS);
    float o0 = (t0-mu)*rstd*n1g[d0]   + n1b[d0];
    float o1 = (t1-mu)*rstd*n1g[d0+1] + n1b[d0+1];
    unsigned int pk = (unsigned int)f2bf(o0) | ((unsigned int)f2bf(o1) << 16);
    *(unsigned int*)(x1b + (size_t)n*DIM + d0) = pk;
}

// ---------------- fused FFN(l) + QKVS(l+1): 32-row tiles, 8 waves (512 thr) ------------
__global__ __launch_bounds__(512) void ffn_qkvs_kernel(
    const unsigned short* __restrict__ x1b,
    const float* __restrict__ hin,
    const unsigned short* __restrict__ w1T, const float* __restrict__ b1,
    const unsigned short* __restrict__ w2T, const float* __restrict__ b2,
    const float* __restrict__ n2g, const float* __restrict__ n2b,
    const float* __restrict__ lng, const float* __restrict__ lnb,
    int apply_act, float* __restrict__ h,
    int do_qkvs, const unsigned short* __restrict__ wTn,
    const float* __restrict__ bqn, const float* __restrict__ bkn,
    const float* __restrict__ bvn, const float* __restrict__ bsn,
    unsigned int* __restrict__ qs, unsigned int* __restrict__ kv)
{
    __shared__ char smem[24576];
    char* sA   = smem;            // [32][128] bf16 swz (x1 tile; later new-h tile)
    char* sMid = smem + 8192;     // [32][256] bf16 swz -> later ffout [32][128] f32 swz
    int row0 = blockIdx.x*32;
    {
        int idx = threadIdx.x;    // 512 threads, 512 items: single pass
        int row = idx >> 4, k16 = idx & 15;
        int byte = row*256 + k16*16;  byte ^= (row & 7) << 4;
        s16x8 val = {0,0,0,0,0,0,0,0};
        int grow = row0 + row;
        if (grow < N_NODES) val = *(const s16x8*)(x1b + (size_t)grow*128 + k16*8);
        *(s16x8*)(sA + byte) = val;
    }
    __syncthreads();

    int w = threadIdx.x >> 6, l = threadIdx.x & 63;   // w in 0..7

    // ---- GEMM1: mid = leaky(x1 @ W1 + b1); wave w -> cols w*32..+31 (2 cf)
    {
        int n0 = w*32;
        f32x4 acc[2][2];
        #pragma unroll
        for (int rf=0;rf<2;++rf)
            #pragma unroll
            for (int cf=0;cf<2;++cf) acc[rf][cf] = (f32x4){0.f,0.f,0.f,0.f};
        s16x8 af[2][2], bfr[2][2];
        #pragma unroll
        for (int rf=0;rf<2;++rf){
            int row = rf*16 + (l & 15);
            int byte = row*256 + (l >> 4)*16;  byte ^= (row & 7) << 4;
            af[0][rf] = *(const s16x8*)(sA + byte);
        }
        #pragma unroll
        for (int cf=0;cf<2;++cf){
            int n = n0 + cf*16 + (l & 15);
            bfr[0][cf] = *(const s16x8*)(w1T + (size_t)n*128 + (l >> 4)*8);
        }
        #pragma unroll
        for (int kb = 0; kb < 4; ++kb){
            int cur = kb & 1, nxt = cur ^ 1;
            if (kb < 3){
                #pragma unroll
                for (int rf=0;rf<2;++rf){
                    int row = rf*16 + (l & 15);
                    int byte = row*256 + (kb+1)*64 + (l >> 4)*16;  byte ^= (row & 7) << 4;
                    af[nxt][rf] = *(const s16x8*)(sA + byte);
                }
                #pragma unroll
                for (int cf=0;cf<2;++cf){
                    int n = n0 + cf*16 + (l & 15);
                    bfr[nxt][cf] = *(const s16x8*)(w1T + (size_t)n*128 + (kb+1)*32 + (l >> 4)*8);
                }
            }
            #pragma unroll
            for (int rf=0;rf<2;++rf)
                #pragma unroll
                for (int cf=0;cf<2;++cf)
                    acc[rf][cf] = __builtin_amdgcn_mfma_f32_16x16x32_bf16(af[cur][rf], bfr[cur][cf], acc[rf][cf], 0, 0, 0);
        }
        #pragma unroll
        for (int cf=0;cf<2;++cf){
            int col = n0 + cf*16 + (l & 15);
            float bb = b1[col];
            #pragma unroll
            for (int rf=0;rf<2;++rf){
                #pragma unroll
                for (int r=0;r<4;++r){
                    int row = rf*16 + ((l >> 4) << 2) + r;
                    float val = leaky(acc[rf][cf][r] + bb);
                    int byte = row*512 + col*2;  byte ^= (row & 7) << 4;
                    *(unsigned short*)(sMid + byte) = f2bf(val);
                }
            }
        }
    }
    __syncthreads();

    // ---- GEMM2: ff = mid @ W2; wave w -> cols w*16..+15 (1 cf); K=256
    f32x4 acc2[2];
    {
        int n0 = w*16;
        #pragma unroll
        for (int rf=0;rf<2;++rf) acc2[rf] = (f32x4){0.f,0.f,0.f,0.f};
        s16x8 af[2][2], bfr[2];
        #pragma unroll
        for (int rf=0;rf<2;++rf){
            int row = rf*16 + (l & 15);
            int byte = row*512 + (l >> 4)*16;  byte ^= (row & 7) << 4;
            af[0][rf] = *(const s16x8*)(sMid + byte);
        }
        {
            int n = n0 + (l & 15);
            bfr[0] = *(const s16x8*)(w2T + (size_t)n*256 + (l >> 4)*8);
        }
        #pragma unroll
        for (int kb = 0; kb < 8; ++kb){
            int cur = kb & 1, nxt = cur ^ 1;
            if (kb < 7){
                #pragma unroll
                for (int rf=0;rf<2;++rf){
                    int row = rf*16 + (l & 15);
                    int byte = row*512 + (kb+1)*64 + (l >> 4)*16;  byte ^= (row & 7) << 4;
                    af[nxt][rf] = *(const s16x8*)(sMid + byte);
                }
                {
                    int n = n0 + (l & 15);
                    bfr[nxt] = *(const s16x8*)(w2T + (size_t)n*256 + (kb+1)*32 + (l >> 4)*8);
                }
            }
            #pragma unroll
            for (int rf=0;rf<2;++rf)
                acc2[rf] = __builtin_amdgcn_mfma_f32_16x16x32_bf16(af[cur][rf], bfr[cur], acc2[rf], 0, 0, 0);
        }
    }
    __syncthreads();   // all GEMM2 reads of sMid done; reuse as ffout f32

    float* sFF = (float*)sMid;   // [32][128] f32 swz
    {
        int col = w*16 + (l & 15);
        float bb = b2[col];
        #pragma unroll
        for (int rf=0;rf<2;++rf){
            #pragma unroll
            for (int r=0;r<4;++r){
                int row = rf*16 + ((l >> 4) << 2) + r;
                int byte = row*512 + col*4;  byte ^= (row & 7) << 4;
                *(float*)((char*)sFF + byte) = acc2[rf][r] + bb;
            }
        }
    }
    __syncthreads();

    // ---- LN chain: c = LN2(x1+ff), hn = LN3(c), act, h = hn + h_in (4 rows/wave)
    int d0 = l*2;
    float g2a = n2g[d0], g2b = n2g[d0+1], be2a = n2b[d0], be2b = n2b[d0+1];
    float gla = lng[d0], glb = lng[d0+1], bla = lnb[d0], blb = lnb[d0+1];
    float2 hrv[4];
    #pragma unroll
    for (int i = 0; i < 4; ++i){
        int grow = row0 + w*4 + i;
        hrv[i] = make_float2(0.f, 0.f);
        if (grow < N_NODES) hrv[i] = *(const float2*)(hin + (size_t)grow*DIM + d0);
    }
    #pragma unroll
    for (int i = 0; i < 4; ++i){
        int rr = w*4 + i;
        int grow = row0 + rr;
        if (grow >= N_NODES) break;
        int byte = rr*512 + d0*4;  byte ^= (rr & 7) << 4;
        float2 ff = *(float2*)((char*)sFF + byte);
        int byteA = rr*256 + d0*2;  byteA ^= (rr & 7) << 4;
        unsigned int xu = *(unsigned int*)(sA + byteA);   // x1 residual from LDS bf16
        float t0 = bflo(xu) + ff.x, t1 = bfhi(xu) + ff.y;
        float sum = sum64(t0 + t1);
        float ss  = sum64(t0*t0 + t1*t1);
        float mu = sum*(1.f/DIM);
        float rstd = rsqrtf(ss*(1.f/DIM) - mu*mu + LN_EPS);
        float c0 = (t0-mu)*rstd*g2a + be2a;
        float c1 = (t1-mu)*rstd*g2b + be2b;
        float sum2 = sum64(c0 + c1);
        float ss2  = sum64(c0*c0 + c1*c1);
        float mu2 = sum2*(1.f/DIM);
        float rstd2 = rsqrtf(ss2*(1.f/DIM) - mu2*mu2 + LN_EPS);
        float z0 = (c0-mu2)*rstd2*gla + bla;
        float z1 = (c1-mu2)*rstd2*glb + blb;
        if (apply_act){ z0 = leaky(z0); z1 = leaky(z1); }
        float o0 = z0 + hrv[i].x, o1 = z1 + hrv[i].y;
        *(float2*)(h + (size_t)grow*DIM + d0) = make_float2(o0, o1);
        unsigned int pk = (unsigned int)f2bf(o0) | ((unsigned int)f2bf(o1) << 16);
        *(unsigned int*)(sA + byteA) = pk;            // new-h bf16 into sA
    }

    if (!do_qkvs) return;
    __syncthreads();   // sA now holds the new-h bf16 tile

    // ---- QKVS for next layer from sA; waves 0-3 take y=0, waves 4-7 take y=1
    {
        int y  = w >> 2;
        int w4 = w & 3;
        int pb0 = y ? 128 : 0;
        int pb1 = y ? 256 : 384;
        f32x4 acc[2][4];
        #pragma unroll
        for (int rf=0;rf<2;++rf)
            #pragma unroll
            for (int cf=0;cf<4;++cf) acc[rf][cf] = (f32x4){0.f,0.f,0.f,0.f};
        s16x8 af[2][2], bf[2][4];
        #pragma unroll
        for (int rf=0;rf<2;++rf){
            int row = rf*16 + (l & 15);
            int byte = row*256 + (l >> 4)*16;  byte ^= (row & 7) << 4;
            af[0][rf] = *(const s16x8*)(sA + byte);
        }
        #pragma unroll
        for (int cf=0;cf<4;++cf){
            int nrow = ((cf < 2) ? pb0 : pb1) + (w4<<5) + ((cf&1)<<4) + (l & 15);
            bf[0][cf] = *(const s16x8*)(wTn + (size_t)nrow*128 + (l >> 4)*8);
        }
        #pragma unroll
        for (int kb = 0; kb < 4; ++kb){
            int cur = kb & 1, nxt = cur ^ 1;
            if (kb < 3){
                #pragma unroll
                for (int rf=0;rf<2;++rf){
                    int row = rf*16 + (l & 15);
                    int byte = row*256 + (kb+1)*64 + (l >> 4)*16;  byte ^= (row & 7) << 4;
                    af[nxt][rf] = *(const s16x8*)(sA + byte);
                }
                #pragma unroll
                for (int cf=0;cf<4;++cf){
                    int nrow = ((cf < 2) ? pb0 : pb1) + (w4<<5) + ((cf&1)<<4) + (l & 15);
                    bf[nxt][cf] = *(const s16x8*)(wTn + (size_t)nrow*128 + (kb+1)*32 + (l >> 4)*8);
                }
            }
            #pragma unroll
            for (int rf=0;rf<2;++rf)
                #pragma unroll
                for (int cf=0;cf<4;++cf)
                    acc[rf][cf] = __builtin_amdgcn_mfma_f32_16x16x32_bf16(af[cur][rf], bf[cur][cf], acc[rf][cf], 0, 0, 0);
        }
        const float* biasLo = y ? bkn : bqn;
        const float* biasHi = y ? bvn : bsn;
        unsigned int* outp  = y ? kv : qs;
        #pragma unroll
        for (int cp = 0; cp < 2; ++cp){
            int col = (w4<<5) + (cp<<4) + (l & 15);
            float blo = biasLo[col], bhi = biasHi[col];
            #pragma unroll
            for (int rf=0;rf<2;++rf){
                #pragma unroll
                for (int r=0;r<4;++r){
                    int row = row0 + rf*16 + ((l >> 4) << 2) + r;
                    if (row < N_NODES){
                        float lo = acc[rf][cp][r]   + blo;
                        float hi = acc[rf][cp+2][r] + bhi;
                        outp[(size_t)row*128 + col] =
                            (unsigned int)f2bf(lo) | ((unsigned int)f2bf(hi) << 16);
                    }
                }
            }
        }
    }
}

extern "C" void kernel_launch(void* const* d_in, const int* in_sizes, int n_in,
                              void* d_out, int out_size, void* d_ws, size_t ws_size,
                              hipStream_t stream)
{
    const int*   edge_index = (const int*)  d_in[1];
    const float* edge_attr  = (const float*)d_in[2];
    const float* node_table = (const float*)d_in[3];
    const float* Wee = (const float*)d_in[4];
    const float* bee = (const float*)d_in[5];
    const float* Wq  = (const float*)d_in[6];  const float* bq = (const float*)d_in[7];
    const float* Wk  = (const float*)d_in[8];  const float* bk = (const float*)d_in[9];
    const float* Wv  = (const float*)d_in[10]; const float* bv = (const float*)d_in[11];
    const float* We  = (const float*)d_in[12]; const float* be = (const float*)d_in[13];
    const float* Ws  = (const float*)d_in[14]; const float* bs = (const float*)d_in[15];
    const float* W1  = (const float*)d_in[16]; const float* b1 = (const float*)d_in[17];
    const float* W2  = (const float*)d_in[18]; const float* b2 = (const float*)d_in[19];
    const float* n1g = (const float*)d_in[20]; const float* n1b = (const float*)d_in[21];
    const float* n2g = (const float*)d_in[22]; const float* n2b = (const float*)d_in[23];
    const float* lng = (const float*)d_in[24]; const float* lnb = (const float*)d_in[25];

    float* h = (float*)d_out;

    char* ws = (char*)d_ws;
    size_t off = 0;
    auto alloc = [&](size_t bytes)->void*{
        void* p = ws + off;
        off += (bytes + 255) & ~(size_t)255;
        return p;
    };
    unsigned int*   qs   = (unsigned int*)  alloc(sizeof(int)*(size_t)N_NODES*DIM);
    unsigned int*   kv   = (unsigned int*)  alloc(sizeof(int)*(size_t)N_NODES*DIM);
    unsigned short* hb   = (unsigned short*)alloc(sizeof(short)*(size_t)N_NODES*DIM);
    unsigned short* x1b  = (unsigned short*)alloc(sizeof(short)*(size_t)N_NODES*DIM);
    unsigned int*   eab  = (unsigned int*)  alloc(sizeof(int)*(size_t)N_EDGES*4);
    unsigned short* wqkvsT = (unsigned short*)alloc(sizeof(short)*NLAYER*512*128);
    unsigned short* w1T    = (unsigned short*)alloc(sizeof(short)*NLAYER*256*128);
    unsigned short* w2T    = (unsigned short*)alloc(sizeof(short)*NLAYER*128*256);
    float* weff = (float*)alloc(sizeof(float)*NLAYER*8*DIM);
    int* rowptr = (int*)alloc(sizeof(int)*(N_NODES+1));
    int* cnt    = (int*)alloc(sizeof(int)*N_NODES);
    int* fill   = (int*)alloc(sizeof(int)*N_NODES);
    int* srcs   = (int*)alloc(sizeof(int)*N_EDGES);
    int* bsum   = (int*)alloc(sizeof(int)*64);
    int* boff   = (int*)alloc(sizeof(int)*64);

    const int* srcIdx = edge_index;
    const int* dstIdx = edge_index + N_EDGES;
    int nb = (N_NODES + 1023)/1024;

    init_h_kernel<<<(N_NODES*DIM+255)/256, 256, 0, stream>>>(node_table, h, hb);
    zero2_kernel<<<(N_NODES+255)/256, 256, 0, stream>>>(cnt, fill);
    count_kernel<<<(N_EDGES+255)/256, 256, 0, stream>>>(dstIdx, cnt);
    scan1_kernel<<<nb, 1024, 0, stream>>>(cnt, rowptr, bsum);
    scan2_kernel<<<1, 64, 0, stream>>>(bsum, boff, nb, rowptr + N_NODES);
    scan3_kernel<<<nb, 1024, 0, stream>>>(rowptr, boff);
    scatter_kernel<<<(N_EDGES+255)/256, 256, 0, stream>>>(srcIdx, dstIdx, edge_attr,
                                                          rowptr, fill, srcs, eab);
    prepw_kernel<<<(NLAYER*131072+255)/256, 256, 0, stream>>>(Wq, Wk, Wv, Ws, W1, W2,
                                                              wqkvsT, w1T, w2T);
    weff_all_kernel<<<NLAYER, 128, 0, stream>>>(Wee, bee, We, be, weff);

    int tiles32 = (N_NODES + 31)/32;
    qkvs_mfma_kernel<<<dim3(tiles32, 2), 256, 0, stream>>>(hb, wqkvsT,
        bq, bk, bv, bs, qs, kv);
    for (int l = 0; l < NLAYER; ++l){
        attn_kernel<<<(N_NODES+3)/4, 256, 0, stream>>>(qs, kv,
            weff + (size_t)l*8*DIM, rowptr, srcs, eab, h,
            n1g + (size_t)l*DIM, n1b + (size_t)l*DIM, x1b);
        int has = (l < NLAYER-1);
        ffn_qkvs_kernel<<<tiles32, 512, 0, stream>>>(x1b, h,
            w1T + (size_t)l*32768, b1 + (size_t)l*2*DIM,
            w2T + (size_t)l*32768, b2 + (size_t)l*DIM,
            n2g + (size_t)l*DIM, n2b + (size_t)l*DIM,
            lng + (size_t)l*DIM, lnb + (size_t)l*DIM,
            has, h,
            has, wqkvsT + (size_t)(l+1 < NLAYER ? l+1 : 0)*65536,
            bq + (size_t)(l+1 < NLAYER ? l+1 : 0)*DIM,
            bk + (size_t)(l+1 < NLAYER ? l+1 : 0)*DIM,
            bv + (size_t)(l+1 < NLAYER ? l+1 : 0)*DIM,
            bs + (size_t)(l+1 < NLAYER ? l+1 : 0)*DIM,
            qs, kv);
    }
}

// Round 28
// 569.525 us; speedup vs baseline: 1.0628x; 1.0628x over previous
//
#include <hip/hip_runtime.h>
#include <hip/hip_bf16.h>
#include <math.h>

#define N_NODES 50000
#define N_EDGES 500000
#define DIM     128
#define NLAYER  4
#define NEFEAT  7

static constexpr float LN_EPS    = 1e-5f;
static constexpr float ATT_SCALE = 0.17677669529663687f;  // 1/sqrt(32)

typedef short s16x8 __attribute__((ext_vector_type(8)));   // 8 bf16 (4 VGPR) MFMA A/B frag
typedef float f32x4 __attribute__((ext_vector_type(4)));   // MFMA C/D frag

static __device__ __forceinline__ float leaky(float x){ return x >= 0.f ? x : 0.01f*x; }

static __device__ __forceinline__ unsigned short f2bf(float f){
    __hip_bfloat16 b = __float2bfloat16(f);
    return *reinterpret_cast<unsigned short*>(&b);
}
static __device__ __forceinline__ float bflo(unsigned int u){ return __uint_as_float(u << 16); }
static __device__ __forceinline__ float bfhi(unsigned int u){ return __uint_as_float(u & 0xFFFF0000u); }

// 16-lane (per-head) sum via DPP row rotations: pure VALU, no LDS pipe.
template<int CTRL>
static __device__ __forceinline__ float dpp_ror_add(float x){
    int r = __builtin_amdgcn_update_dpp(0, __float_as_int(x), CTRL, 0xf, 0xf, true);
    return x + __int_as_float(r);
}
static __device__ __forceinline__ float sum16(float x){
    x = dpp_ror_add<0x128>(x);   // row_ror:8
    x = dpp_ror_add<0x124>(x);   // row_ror:4
    x = dpp_ror_add<0x122>(x);   // row_ror:2
    x = dpp_ror_add<0x121>(x);   // row_ror:1
    return x;
}
static __device__ __forceinline__ float sum64(float x){
    x = sum16(x);
    x += __shfl_xor(x, 16);
    x += __shfl_xor(x, 32);
    return x;
}

// ---------------- init h = node_table[0] broadcast (fp32 + bf16 shadow) ----------------
__global__ void init_h_kernel(const float* __restrict__ node_table,
                              float* __restrict__ h, unsigned short* __restrict__ hb){
    int i = blockIdx.x*blockDim.x + threadIdx.x;
    if (i < N_NODES*DIM){
        float v = node_table[i & (DIM-1)];
        h[i]  = v;
        hb[i] = f2bf(v);
    }
}

// ---------------- CSR build ----------------
__global__ void zero2_kernel(int* __restrict__ a, int* __restrict__ b){
    int i = blockIdx.x*blockDim.x + threadIdx.x;
    if (i < N_NODES){ a[i] = 0; b[i] = 0; }
}

__global__ void count_kernel(const int* __restrict__ dst, int* __restrict__ cnt){
    int e = blockIdx.x*blockDim.x + threadIdx.x;
    if (e < N_EDGES) atomicAdd(&cnt[dst[e]], 1);
}

// parallel scan: per-block exclusive scan + block sums
__global__ void scan1_kernel(const int* __restrict__ cnt, int* __restrict__ rowptr,
                             int* __restrict__ bsum){
    __shared__ int wsum[16];
    int t = threadIdx.x;
    int i = blockIdx.x*1024 + t;
    int lane = t & 63, wid = t >> 6;
    int v = (i < N_NODES) ? cnt[i] : 0;
    int s = v;
    #pragma unroll
    for (int off = 1; off < 64; off <<= 1){
        int tt = __shfl_up(s, off);
        if (lane >= off) s += tt;
    }
    if (lane == 63) wsum[wid] = s;
    __syncthreads();
    if (wid == 0 && lane < 16){
        int x = wsum[lane];
        #pragma unroll
        for (int off = 1; off < 16; off <<= 1){
            int tt = __shfl_up(x, off);
            if (lane >= off) x += tt;
        }
        wsum[lane] = x;
    }
    __syncthreads();
    int wpre = (wid == 0) ? 0 : wsum[wid-1];
    if (i < N_NODES) rowptr[i] = wpre + s - v;      // exclusive within block
    if (t == 1023) bsum[blockIdx.x] = wpre + s;     // block total
}

__global__ void scan2_kernel(const int* __restrict__ bsum, int* __restrict__ boff,
                             int nb, int* __restrict__ totalp){
    int t = threadIdx.x;   // 64 threads
    int v = (t < nb) ? bsum[t] : 0;
    int s = v;
    #pragma unroll
    for (int off = 1; off < 64; off <<= 1){
        int tt = __shfl_up(s, off);
        if (t >= off) s += tt;
    }
    if (t < nb) boff[t] = s - v;
    if (t == 63) *totalp = s;
}

__global__ void scan3_kernel(int* __restrict__ rowptr, const int* __restrict__ boff){
    int i = blockIdx.x*1024 + threadIdx.x;
    if (i < N_NODES) rowptr[i] += boff[blockIdx.x];
}

__global__ void scatter_kernel(const int* __restrict__ src, const int* __restrict__ dst,
                               const float* __restrict__ edge_attr,
                               const int* __restrict__ rowptr, int* __restrict__ fill,
                               int* __restrict__ srcs, unsigned int* __restrict__ eab){
    int e = blockIdx.x*blockDim.x + threadIdx.x;
    if (e >= N_EDGES) return;
    int d   = dst[e];
    int pos = rowptr[d] + atomicAdd(&fill[d], 1);
    srcs[pos] = src[e];
    const float* a = edge_attr + (size_t)e*NEFEAT;
    uint4 u;
    u.x = (unsigned int)f2bf(a[0]) | ((unsigned int)f2bf(a[1]) << 16);
    u.y = (unsigned int)f2bf(a[2]) | ((unsigned int)f2bf(a[3]) << 16);
    u.z = (unsigned int)f2bf(a[4]) | ((unsigned int)f2bf(a[5]) << 16);
    u.w = (unsigned int)f2bf(a[6]) | (0x3F80u << 16);   // bias slot = 1.0
    *(uint4*)(eab + (size_t)pos*4) = u;
}

// ---------------- Weff[l] = [Wee@We_l ; bee@We_l + be_l]  (8 x 128), all layers ----------
__global__ void weff_all_kernel(const float* __restrict__ Wee, const float* __restrict__ bee,
                                const float* __restrict__ We, const float* __restrict__ be,
                                float* __restrict__ weff){
    int l = blockIdx.x;
    int d = threadIdx.x;  // 128 threads
    const float* We_l = We + (size_t)l*DIM*DIM;
    float* out = weff + (size_t)l*8*DIM;
    for (int c = 0; c < NEFEAT; ++c){
        float s = 0.f;
        for (int t = 0; t < DIM; ++t) s += Wee[c*DIM + t] * We_l[t*DIM + d];
        out[c*DIM + d] = s;
    }
    float s = 0.f;
    for (int t = 0; t < DIM; ++t) s += bee[t] * We_l[t*DIM + d];
    out[7*DIM + d] = s + be[l*DIM + d];
}

// ---------------- weight prep: bf16 transposed copies ----------------
__global__ void prepw_kernel(const float* __restrict__ Wq, const float* __restrict__ Wk,
                             const float* __restrict__ Wv, const float* __restrict__ Ws,
                             const float* __restrict__ W1, const float* __restrict__ W2,
                             unsigned short* __restrict__ wqkvsT,
                             unsigned short* __restrict__ w1T,
                             unsigned short* __restrict__ w2T){
    int tid = blockIdx.x*blockDim.x + threadIdx.x;
    if (tid >= NLAYER*131072) return;
    int l = tid >> 17;
    int r = tid & 131071;
    if (r < 65536){
        int n = r >> 7, k = r & 127;
        int p = n >> 7, nn = n & 127;
        const float* W = (p==0)?Wq:(p==1)?Wk:(p==2)?Wv:Ws;
        float val = W[(size_t)l*DIM*DIM + (size_t)k*DIM + nn];
        wqkvsT[(size_t)l*65536 + (size_t)n*128 + k] = f2bf(val);
    } else if (r < 98304){
        int r2 = r - 65536;
        int n = r2 >> 7, k = r2 & 127;
        float val = W1[(size_t)l*32768 + (size_t)k*256 + n];
        w1T[(size_t)l*32768 + (size_t)n*128 + k] = f2bf(val);
    } else {
        int r2 = r - 98304;
        int n = r2 >> 8, k = r2 & 255;
        float val = W2[(size_t)l*32768 + (size_t)k*128 + n];
        w2T[(size_t)l*32768 + (size_t)n*256 + k] = f2bf(val);
    }
}

// ---------------- standalone QKVS (layer 0 only): 32-row tiles ----------------
__global__ __launch_bounds__(256) void qkvs_mfma_kernel(
    const unsigned short* __restrict__ hb, const unsigned short* __restrict__ wT,
    const float* __restrict__ bq, const float* __restrict__ bk,
    const float* __restrict__ bv, const float* __restrict__ bs,
    unsigned int* __restrict__ qs, unsigned int* __restrict__ kv)
{
    __shared__ char sA[32*256];   // [32][128] bf16, XOR-swizzled (8 KB)
    int row0 = blockIdx.x*32;
    for (int idx = threadIdx.x; idx < 512; idx += 256){
        int row = idx >> 4, k16 = idx & 15;
        int byte = row*256 + k16*16;  byte ^= (row & 7) << 4;
        s16x8 val = {0,0,0,0,0,0,0,0};
        int grow = row0 + row;
        if (grow < N_NODES) val = *(const s16x8*)(hb + (size_t)grow*128 + k16*8);
        *(s16x8*)(sA + byte) = val;
    }
    __syncthreads();

    int w = threadIdx.x >> 6, l = threadIdx.x & 63;
    int y = blockIdx.y;
    int pb0 = y ? 128 : 0;
    int pb1 = y ? 256 : 384;

    f32x4 acc[2][4];
    #pragma unroll
    for (int rf=0;rf<2;++rf)
        #pragma unroll
        for (int cf=0;cf<4;++cf) acc[rf][cf] = (f32x4){0.f,0.f,0.f,0.f};

    s16x8 af[2][2], bf[2][4];
    #pragma unroll
    for (int rf=0;rf<2;++rf){
        int row = rf*16 + (l & 15);
        int byte = row*256 + (l >> 4)*16;  byte ^= (row & 7) << 4;
        af[0][rf] = *(const s16x8*)(sA + byte);
    }
    #pragma unroll
    for (int cf=0;cf<4;++cf){
        int nrow = ((cf < 2) ? pb0 : pb1) + (w<<5) + ((cf&1)<<4) + (l & 15);
        bf[0][cf] = *(const s16x8*)(wT + (size_t)nrow*128 + (l >> 4)*8);
    }
    #pragma unroll
    for (int kb = 0; kb < 4; ++kb){
        int cur = kb & 1, nxt = cur ^ 1;
        if (kb < 3){
            #pragma unroll
            for (int rf=0;rf<2;++rf){
                int row = rf*16 + (l & 15);
                int byte = row*256 + (kb+1)*64 + (l >> 4)*16;  byte ^= (row & 7) << 4;
                af[nxt][rf] = *(const s16x8*)(sA + byte);
            }
            #pragma unroll
            for (int cf=0;cf<4;++cf){
                int nrow = ((cf < 2) ? pb0 : pb1) + (w<<5) + ((cf&1)<<4) + (l & 15);
                bf[nxt][cf] = *(const s16x8*)(wT + (size_t)nrow*128 + (kb+1)*32 + (l >> 4)*8);
            }
        }
        #pragma unroll
        for (int rf=0;rf<2;++rf)
            #pragma unroll
            for (int cf=0;cf<4;++cf)
                acc[rf][cf] = __builtin_amdgcn_mfma_f32_16x16x32_bf16(af[cur][rf], bf[cur][cf], acc[rf][cf], 0, 0, 0);
    }

    const float* biasLo = y ? bk : bq;
    const float* biasHi = y ? bv : bs;
    unsigned int* outp  = y ? kv : qs;
    #pragma unroll
    for (int cp = 0; cp < 2; ++cp){
        int col = (w<<5) + (cp<<4) + (l & 15);
        float blo = biasLo[col], bhi = biasHi[col];
        #pragma unroll
        for (int rf=0;rf<2;++rf){
            #pragma unroll
            for (int r=0;r<4;++r){
                int row = row0 + rf*16 + ((l >> 4) << 2) + r;
                if (row < N_NODES){
                    float lo = acc[rf][cp][r]   + blo;
                    float hi = acc[rf][cp+2][r] + bhi;
                    outp[(size_t)row*128 + col] =
                        (unsigned int)f2bf(lo) | ((unsigned int)f2bf(hi) << 16);
                }
            }
        }
    }
}

// ---------------- attention + skip + LN1 fused: one wave per destination node -----------
// Augmented-dot + DPP reductions; unroll-4 edge loop for 4 gathers in flight.
__global__ __launch_bounds__(256) void attn_kernel(
    const unsigned int* __restrict__ qs, const unsigned int* __restrict__ kv,
    const float* __restrict__ weff_l, const int* __restrict__ rowptr,
    const int* __restrict__ srcs, const unsigned int* __restrict__ eab,
    const float* __restrict__ h,
    const float* __restrict__ n1g, const float* __restrict__ n1b,
    unsigned short* __restrict__ x1b)
{
    __shared__ float wf[8][DIM];           // 4 KB
    __shared__ float els[4][64][9];        // per-wave 64-edge feature tile (+pad)
    for (int i = threadIdx.x; i < 8*DIM; i += 256) ((float*)wf)[i] = weff_l[i];
    __syncthreads();
    int wv = threadIdx.x >> 6, lane = threadIdx.x & 63;
    int n = blockIdx.x*4 + wv;
    if (n >= N_NODES) return;
    float (*el)[9] = els[wv];

    int d0 = lane*2;
    int fi = lane & 15;
    int fc = fi & 7;

    uint2 qsb = *(const uint2*)(qs + (size_t)n*DIM + d0);
    float q0 = bflo(qsb.x)*ATT_SCALE, q1 = bflo(qsb.y)*ATT_SCALE;
    float s0 = bfhi(qsb.x), s1 = bfhi(qsb.y);

    float qe[8];
    #pragma unroll
    for (int c = 0; c < 8; ++c){
        float2 wc = *(const float2*)&wf[c][d0];
        qe[c] = sum16(q0*wc.x + q1*wc.y);
    }
    float qaug = qe[0];
    qaug = (fc==1) ? qe[1] : qaug;
    qaug = (fc==2) ? qe[2] : qaug;
    qaug = (fc==3) ? qe[3] : qaug;
    qaug = (fc==4) ? qe[4] : qaug;
    qaug = (fc==5) ? qe[5] : qaug;
    qaug = (fc==6) ? qe[6] : qaug;
    qaug = (fc==7) ? qe[7] : qaug;
    qaug = (fi < 8) ? qaug : 0.f;

    int beg = rowptr[n], deg = rowptr[n+1] - beg;
    float a0 = 0.f, a1 = 0.f, peaL = 0.f;

    for (int cb = 0; cb < deg; cb += 64){
        int base = beg + cb;
        int cdeg = deg - cb; if (cdeg > 64) cdeg = 64;
        int srcv = 0;
        uint4 eu = {0u,0u,0u,0u};
        if (cb + lane < deg){
            srcv = srcs[base + lane];
            eu = *(const uint4*)(eab + ((size_t)(base + lane) << 2));
        }
        asm volatile("s_waitcnt lgkmcnt(0)" ::: "memory");
        __builtin_amdgcn_sched_barrier(0);
        {
            float* row = el[lane];
            row[0] = bflo(eu.x); row[1] = bfhi(eu.x);
            row[2] = bflo(eu.y); row[3] = bfhi(eu.y);
            row[4] = bflo(eu.z); row[5] = bfhi(eu.z);
            row[6] = bflo(eu.w); row[7] = bfhi(eu.w);   // bias slot = 1.0
        }
        asm volatile("s_waitcnt lgkmcnt(0)" ::: "memory");
        __builtin_amdgcn_sched_barrier(0);

        int j = 0;
        for (; j + 3 < cdeg; j += 4){
            int svA = __builtin_amdgcn_readlane(srcv, j);
            int svB = __builtin_amdgcn_readlane(srcv, j+1);
            int svC = __builtin_amdgcn_readlane(srcv, j+2);
            int svD = __builtin_amdgcn_readlane(srcv, j+3);
            uint2 kvA = *(const uint2*)(kv + (size_t)svA*DIM + d0);
            uint2 kvB = *(const uint2*)(kv + (size_t)svB*DIM + d0);
            uint2 kvC = *(const uint2*)(kv + (size_t)svC*DIM + d0);
            uint2 kvD = *(const uint2*)(kv + (size_t)svD*DIM + d0);
            float eaA = el[j][fc];
            float eaB = el[j+1][fc];
            float eaC = el[j+2][fc];
            float eaD = el[j+3][fc];
            float pA = sum16(q0*bflo(kvA.x) + q1*bflo(kvA.y) + qaug*eaA);
            float pB = sum16(q0*bflo(kvB.x) + q1*bflo(kvB.y) + qaug*eaB);
            float pC = sum16(q0*bflo(kvC.x) + q1*bflo(kvC.y) + qaug*eaC);
            float pD = sum16(q0*bflo(kvD.x) + q1*bflo(kvD.y) + qaug*eaD);
            float ppA = __expf(pA);
            float ppB = __expf(pB);
            float ppC = __expf(pC);
            float ppD = __expf(pD);
            a0   += ppA*bfhi(kvA.x) + ppB*bfhi(kvB.x) + ppC*bfhi(kvC.x) + ppD*bfhi(kvD.x);
            a1   += ppA*bfhi(kvA.y) + ppB*bfhi(kvB.y) + ppC*bfhi(kvC.y) + ppD*bfhi(kvD.y);
            peaL += ppA*eaA + ppB*eaB + ppC*eaC + ppD*eaD;
        }
        for (; j < cdeg; ++j){
            int sv = __builtin_amdgcn_readlane(srcv, j);
            uint2 kva = *(const uint2*)(kv + (size_t)sv*DIM + d0);
            float ea = el[j][fc];
            float p = sum16(q0*bflo(kva.x) + q1*bflo(kva.y) + qaug*ea);
            float pp = __expf(p);
            a0   += pp*bfhi(kva.x);
            a1   += pp*bfhi(kva.y);
            peaL += pp*ea;
        }
    }

    int hb_ = lane & 48;
    float pc0 = __shfl(peaL, hb_ + 0);
    float pc1 = __shfl(peaL, hb_ + 1);
    float pc2 = __shfl(peaL, hb_ + 2);
    float pc3 = __shfl(peaL, hb_ + 3);
    float pc4 = __shfl(peaL, hb_ + 4);
    float pc5 = __shfl(peaL, hb_ + 5);
    float pc6 = __shfl(peaL, hb_ + 6);
    float den = __shfl(peaL, hb_ + 7);    // ea7 == 1 -> pea7 == sum(exp)

    float inv = (den > 0.f) ? 1.f/den : 0.f;
    float ev0, ev1;
    {
        float2 w0 = *(const float2*)&wf[0][d0];
        float2 w1c = *(const float2*)&wf[1][d0];
        float2 w2c = *(const float2*)&wf[2][d0];
        float2 w3c = *(const float2*)&wf[3][d0];
        float2 w4c = *(const float2*)&wf[4][d0];
        float2 w5c = *(const float2*)&wf[5][d0];
        float2 w6c = *(const float2*)&wf[6][d0];
        float2 w7c = *(const float2*)&wf[7][d0];
        ev0 = pc0*w0.x + pc1*w1c.x + pc2*w2c.x + pc3*w3c.x
            + pc4*w4c.x + pc5*w5c.x + pc6*w6c.x + den*w7c.x;
        ev1 = pc0*w0.y + pc1*w1c.y + pc2*w2c.y + pc3*w3c.y
            + pc4*w4c.y + pc5*w5c.y + pc6*w6c.y + den*w7c.y;
    }

    float2 hv = *(const float2*)(h + (size_t)n*DIM + d0);
    float t0 = hv.x + (a0 + ev0)*inv + s0;
    float t1 = hv.y + (a1 + ev1)*inv + s1;
    float sum = sum64(t0 + t1);
    float ss  = sum64(t0*t0 + t1*t1);
    float mu = sum * (1.f/DIM);
    float rstd = rsqrtf(ss*(1.f/DIM) - mu*mu + LN_EPS);
    float o0 = (t0-mu)*rstd*n1g[d0]   + n1b[d0];
    float o1 = (t1-mu)*rstd*n1g[d0+1] + n1b[d0+1];
    unsigned int pk = (unsigned int)f2bf(o0) | ((unsigned int)f2bf(o1) << 16);
    *(unsigned int*)(x1b + (size_t)n*DIM + d0) = pk;
}

// ---------------- fused FFN(l) + QKVS(l+1): 32-row tiles ----------------
__global__ __launch_bounds__(256) void ffn_qkvs_kernel(
    const unsigned short* __restrict__ x1b,
    const float* __restrict__ hin,
    const unsigned short* __restrict__ w1T, const float* __restrict__ b1,
    const unsigned short* __restrict__ w2T, const float* __restrict__ b2,
    const float* __restrict__ n2g, const float* __restrict__ n2b,
    const float* __restrict__ lng, const float* __restrict__ lnb,
    int apply_act, float* __restrict__ h,
    int do_qkvs, const unsigned short* __restrict__ wTn,
    const float* __restrict__ bqn, const float* __restrict__ bkn,
    const float* __restrict__ bvn, const float* __restrict__ bsn,
    unsigned int* __restrict__ qs, unsigned int* __restrict__ kv)
{
    __shared__ char smem[24576];
    char* sA   = smem;            // [32][128] bf16 swz (x1 tile; later new-h tile)
    char* sMid = smem + 8192;     // [32][256] bf16 swz -> later ffout [32][128] f32 swz
    int row0 = blockIdx.x*32;
    for (int idx = threadIdx.x; idx < 512; idx += 256){
        int row = idx >> 4, k16 = idx & 15;
        int byte = row*256 + k16*16;  byte ^= (row & 7) << 4;
        s16x8 val = {0,0,0,0,0,0,0,0};
        int grow = row0 + row;
        if (grow < N_NODES) val = *(const s16x8*)(x1b + (size_t)grow*128 + k16*8);
        *(s16x8*)(sA + byte) = val;
    }
    __syncthreads();

    int w = threadIdx.x >> 6, l = threadIdx.x & 63;

    // ---- GEMM1: mid = leaky(x1 @ W1 + b1); wave w -> cols w*64..+63
    {
        int n0 = w*64;
        f32x4 acc[2][4];
        #pragma unroll
        for (int rf=0;rf<2;++rf)
            #pragma unroll
            for (int cf=0;cf<4;++cf) acc[rf][cf] = (f32x4){0.f,0.f,0.f,0.f};
        s16x8 af[2][2], bfr[2][4];
        #pragma unroll
        for (int rf=0;rf<2;++rf){
            int row = rf*16 + (l & 15);
            int byte = row*256 + (l >> 4)*16;  byte ^= (row & 7) << 4;
            af[0][rf] = *(const s16x8*)(sA + byte);
        }
        #pragma unroll
        for (int cf=0;cf<4;++cf){
            int n = n0 + cf*16 + (l & 15);
            bfr[0][cf] = *(const s16x8*)(w1T + (size_t)n*128 + (l >> 4)*8);
        }
        #pragma unroll
        for (int kb = 0; kb < 4; ++kb){
            int cur = kb & 1, nxt = cur ^ 1;
            if (kb < 3){
                #pragma unroll
                for (int rf=0;rf<2;++rf){
                    int row = rf*16 + (l & 15);
                    int byte = row*256 + (kb+1)*64 + (l >> 4)*16;  byte ^= (row & 7) << 4;
                    af[nxt][rf] = *(const s16x8*)(sA + byte);
                }
                #pragma unroll
                for (int cf=0;cf<4;++cf){
                    int n = n0 + cf*16 + (l & 15);
                    bfr[nxt][cf] = *(const s16x8*)(w1T + (size_t)n*128 + (kb+1)*32 + (l >> 4)*8);
                }
            }
            #pragma unroll
            for (int rf=0;rf<2;++rf)
                #pragma unroll
                for (int cf=0;cf<4;++cf)
                    acc[rf][cf] = __builtin_amdgcn_mfma_f32_16x16x32_bf16(af[cur][rf], bfr[cur][cf], acc[rf][cf], 0, 0, 0);
        }
        #pragma unroll
        for (int cf=0;cf<4;++cf){
            int col = n0 + cf*16 + (l & 15);
            float bb = b1[col];
            #pragma unroll
            for (int rf=0;rf<2;++rf){
                #pragma unroll
                for (int r=0;r<4;++r){
                    int row = rf*16 + ((l >> 4) << 2) + r;
                    float val = leaky(acc[rf][cf][r] + bb);
                    int byte = row*512 + col*2;  byte ^= (row & 7) << 4;
                    *(unsigned short*)(sMid + byte) = f2bf(val);
                }
            }
        }
    }
    __syncthreads();

    // ---- GEMM2: ff = mid @ W2; wave w -> cols w*32..+31; K=256
    f32x4 acc2[2][2];
    {
        int n0 = w*32;
        #pragma unroll
        for (int cf=0;cf<2;++cf)
            #pragma unroll
            for (int rf=0;rf<2;++rf) acc2[cf][rf] = (f32x4){0.f,0.f,0.f,0.f};
        s16x8 af[2][2], bfr[2][2];
        #pragma unroll
        for (int rf=0;rf<2;++rf){
            int row = rf*16 + (l & 15);
            int byte = row*512 + (l >> 4)*16;  byte ^= (row & 7) << 4;
            af[0][rf] = *(const s16x8*)(sMid + byte);
        }
        #pragma unroll
        for (int cf=0;cf<2;++cf){
            int n = n0 + cf*16 + (l & 15);
            bfr[0][cf] = *(const s16x8*)(w2T + (size_t)n*256 + (l >> 4)*8);
        }
        #pragma unroll
        for (int kb = 0; kb < 8; ++kb){
            int cur = kb & 1, nxt = cur ^ 1;
            if (kb < 7){
                #pragma unroll
                for (int rf=0;rf<2;++rf){
                    int row = rf*16 + (l & 15);
                    int byte = row*512 + (kb+1)*64 + (l >> 4)*16;  byte ^= (row & 7) << 4;
                    af[nxt][rf] = *(const s16x8*)(sMid + byte);
                }
                #pragma unroll
                for (int cf=0;cf<2;++cf){
                    int n = n0 + cf*16 + (l & 15);
                    bfr[nxt][cf] = *(const s16x8*)(w2T + (size_t)n*256 + (kb+1)*32 + (l >> 4)*8);
                }
            }
            #pragma unroll
            for (int cf=0;cf<2;++cf)
                #pragma unroll
                for (int rf=0;rf<2;++rf)
                    acc2[cf][rf] = __builtin_amdgcn_mfma_f32_16x16x32_bf16(af[cur][rf], bfr[cur][cf], acc2[cf][rf], 0, 0, 0);
        }
    }
    __syncthreads();   // all GEMM2 reads of sMid done; reuse as ffout f32

    float* sFF = (float*)sMid;   // [32][128] f32 swz
    {
        int n0 = w*32;
        #pragma unroll
        for (int cf=0;cf<2;++cf){
            int col = n0 + cf*16 + (l & 15);
            float bb = b2[col];
            #pragma unroll
            for (int rf=0;rf<2;++rf){
                #pragma unroll
                for (int r=0;r<4;++r){
                    int row = rf*16 + ((l >> 4) << 2) + r;
                    int byte = row*512 + col*4;  byte ^= (row & 7) << 4;
                    *(float*)((char*)sFF + byte) = acc2[cf][rf][r] + bb;
                }
            }
        }
    }
    __syncthreads();

    // ---- LN chain: c = LN2(x1+ff), hn = LN3(c), act, h = hn + h_in
    int d0 = l*2;
    float g2a = n2g[d0], g2b = n2g[d0+1], be2a = n2b[d0], be2b = n2b[d0+1];
    float gla = lng[d0], glb = lng[d0+1], bla = lnb[d0], blb = lnb[d0+1];
    float2 hrv[8];
    #pragma unroll
    for (int i = 0; i < 8; ++i){
        int grow = row0 + w*8 + i;
        hrv[i] = make_float2(0.f, 0.f);
        if (grow < N_NODES) hrv[i] = *(const float2*)(hin + (size_t)grow*DIM + d0);
    }
    #pragma unroll
    for (int i = 0; i < 8; ++i){
        int rr = w*8 + i;
        int grow = row0 + rr;
        if (grow >= N_NODES) break;
        int byte = rr*512 + d0*4;  byte ^= (rr & 7) << 4;
        float2 ff = *(float2*)((char*)sFF + byte);
        int byteA = rr*256 + d0*2;  byteA ^= (rr & 7) << 4;
        unsigned int xu = *(unsigned int*)(sA + byteA);   // x1 residual from LDS bf16
        float t0 = bflo(xu) + ff.x, t1 = bfhi(xu) + ff.y;
        float sum = sum64(t0 + t1);
        float ss  = sum64(t0*t0 + t1*t1);
        float mu = sum*(1.f/DIM);
        float rstd = rsqrtf(ss*(1.f/DIM) - mu*mu + LN_EPS);
        float c0 = (t0-mu)*rstd*g2a + be2a;
        float c1 = (t1-mu)*rstd*g2b + be2b;
        float sum2 = sum64(c0 + c1);
        float ss2  = sum64(c0*c0 + c1*c1);
        float mu2 = sum2*(1.f/DIM);
        float rstd2 = rsqrtf(ss2*(1.f/DIM) - mu2*mu2 + LN_EPS);
        float z0 = (c0-mu2)*rstd2*gla + bla;
        float z1 = (c1-mu2)*rstd2*glb + blb;
        if (apply_act){ z0 = leaky(z0); z1 = leaky(z1); }
        float o0 = z0 + hrv[i].x, o1 = z1 + hrv[i].y;
        *(float2*)(h + (size_t)grow*DIM + d0) = make_float2(o0, o1);
        unsigned int pk = (unsigned int)f2bf(o0) | ((unsigned int)f2bf(o1) << 16);
        *(unsigned int*)(sA + byteA) = pk;            // new-h bf16 into sA
    }

    if (!do_qkvs) return;
    __syncthreads();   // sA now holds the new-h bf16 tile

    // ---- QKVS for next layer from sA; loop both part-pairs
    #pragma unroll
    for (int y = 0; y < 2; ++y){
        int pb0 = y ? 128 : 0;
        int pb1 = y ? 256 : 384;
        f32x4 acc[2][4];
        #pragma unroll
        for (int rf=0;rf<2;++rf)
            #pragma unroll
            for (int cf=0;cf<4;++cf) acc[rf][cf] = (f32x4){0.f,0.f,0.f,0.f};
        s16x8 af[2][2], bf[2][4];
        #pragma unroll
        for (int rf=0;rf<2;++rf){
            int row = rf*16 + (l & 15);
            int byte = row*256 + (l >> 4)*16;  byte ^= (row & 7) << 4;
            af[0][rf] = *(const s16x8*)(sA + byte);
        }
        #pragma unroll
        for (int cf=0;cf<4;++cf){
            int nrow = ((cf < 2) ? pb0 : pb1) + (w<<5) + ((cf&1)<<4) + (l & 15);
            bf[0][cf] = *(const s16x8*)(wTn + (size_t)nrow*128 + (l >> 4)*8);
        }
        #pragma unroll
        for (int kb = 0; kb < 4; ++kb){
            int cur = kb & 1, nxt = cur ^ 1;
            if (kb < 3){
                #pragma unroll
                for (int rf=0;rf<2;++rf){
                    int row = rf*16 + (l & 15);
                    int byte = row*256 + (kb+1)*64 + (l >> 4)*16;  byte ^= (row & 7) << 4;
                    af[nxt][rf] = *(const s16x8*)(sA + byte);
                }
                #pragma unroll
                for (int cf=0;cf<4;++cf){
                    int nrow = ((cf < 2) ? pb0 : pb1) + (w<<5) + ((cf&1)<<4) + (l & 15);
                    bf[nxt][cf] = *(const s16x8*)(wTn + (size_t)nrow*128 + (kb+1)*32 + (l >> 4)*8);
                }
            }
            #pragma unroll
            for (int rf=0;rf<2;++rf)
                #pragma unroll
                for (int cf=0;cf<4;++cf)
                    acc[rf][cf] = __builtin_amdgcn_mfma_f32_16x16x32_bf16(af[cur][rf], bf[cur][cf], acc[rf][cf], 0, 0, 0);
        }
        const float* biasLo = y ? bkn : bqn;
        const float* biasHi = y ? bvn : bsn;
        unsigned int* outp  = y ? kv : qs;
        #pragma unroll
        for (int cp = 0; cp < 2; ++cp){
            int col = (w<<5) + (cp<<4) + (l & 15);
            float blo = biasLo[col], bhi = biasHi[col];
            #pragma unroll
            for (int rf=0;rf<2;++rf){
                #pragma unroll
                for (int r=0;r<4;++r){
                    int row = row0 + rf*16 + ((l >> 4) << 2) + r;
                    if (row < N_NODES){
                        float lo = acc[rf][cp][r]   + blo;
                        float hi = acc[rf][cp+2][r] + bhi;
                        outp[(size_t)row*128 + col] =
                            (unsigned int)f2bf(lo) | ((unsigned int)f2bf(hi) << 16);
                    }
                }
            }
        }
    }
}

extern "C" void kernel_launch(void* const* d_in, const int* in_sizes, int n_in,
                              void* d_out, int out_size, void* d_ws, size_t ws_size,
                              hipStream_t stream)
{
    const int*   edge_index = (const int*)  d_in[1];
    const float* edge_attr  = (const float*)d_in[2];
    const float* node_table = (const float*)d_in[3];
    const float* Wee = (const float*)d_in[4];
    const float* bee = (const float*)d_in[5];
    const float* Wq  = (const float*)d_in[6];  const float* bq = (const float*)d_in[7];
    const float* Wk  = (const float*)d_in[8];  const float* bk = (const float*)d_in[9];
    const float* Wv  = (const float*)d_in[10]; const float* bv = (const float*)d_in[11];
    const float* We  = (const float*)d_in[12]; const float* be = (const float*)d_in[13];
    const float* Ws  = (const float*)d_in[14]; const float* bs = (const float*)d_in[15];
    const float* W1  = (const float*)d_in[16]; const float* b1 = (const float*)d_in[17];
    const float* W2  = (const float*)d_in[18]; const float* b2 = (const float*)d_in[19];
    const float* n1g = (const float*)d_in[20]; const float* n1b = (const float*)d_in[21];
    const float* n2g = (const float*)d_in[22]; const float* n2b = (const float*)d_in[23];
    const float* lng = (const float*)d_in[24]; const float* lnb = (const float*)d_in[25];

    float* h = (float*)d_out;

    char* ws = (char*)d_ws;
    size_t off = 0;
    auto alloc = [&](size_t bytes)->void*{
        void* p = ws + off;
        off += (bytes + 255) & ~(size_t)255;
        return p;
    };
    unsigned int*   qs   = (unsigned int*)  alloc(sizeof(int)*(size_t)N_NODES*DIM);
    unsigned int*   kv   = (unsigned int*)  alloc(sizeof(int)*(size_t)N_NODES*DIM);
    unsigned short* hb   = (unsigned short*)alloc(sizeof(short)*(size_t)N_NODES*DIM);
    unsigned short* x1b  = (unsigned short*)alloc(sizeof(short)*(size_t)N_NODES*DIM);
    unsigned int*   eab  = (unsigned int*)  alloc(sizeof(int)*(size_t)N_EDGES*4);
    unsigned short* wqkvsT = (unsigned short*)alloc(sizeof(short)*NLAYER*512*128);
    unsigned short* w1T    = (unsigned short*)alloc(sizeof(short)*NLAYER*256*128);
    unsigned short* w2T    = (unsigned short*)alloc(sizeof(short)*NLAYER*128*256);
    float* weff = (float*)alloc(sizeof(float)*NLAYER*8*DIM);
    int* rowptr = (int*)alloc(sizeof(int)*(N_NODES+1));
    int* cnt    = (int*)alloc(sizeof(int)*N_NODES);
    int* fill   = (int*)alloc(sizeof(int)*N_NODES);
    int* srcs   = (int*)alloc(sizeof(int)*N_EDGES);
    int* bsum   = (int*)alloc(sizeof(int)*64);
    int* boff   = (int*)alloc(sizeof(int)*64);

    const int* srcIdx = edge_index;
    const int* dstIdx = edge_index + N_EDGES;
    int nb = (N_NODES + 1023)/1024;

    init_h_kernel<<<(N_NODES*DIM+255)/256, 256, 0, stream>>>(node_table, h, hb);
    zero2_kernel<<<(N_NODES+255)/256, 256, 0, stream>>>(cnt, fill);
    count_kernel<<<(N_EDGES+255)/256, 256, 0, stream>>>(dstIdx, cnt);
    scan1_kernel<<<nb, 1024, 0, stream>>>(cnt, rowptr, bsum);
    scan2_kernel<<<1, 64, 0, stream>>>(bsum, boff, nb, rowptr + N_NODES);
    scan3_kernel<<<nb, 1024, 0, stream>>>(rowptr, boff);
    scatter_kernel<<<(N_EDGES+255)/256, 256, 0, stream>>>(srcIdx, dstIdx, edge_attr,
                                                          rowptr, fill, srcs, eab);
    prepw_kernel<<<(NLAYER*131072+255)/256, 256, 0, stream>>>(Wq, Wk, Wv, Ws, W1, W2,
                                                              wqkvsT, w1T, w2T);
    weff_all_kernel<<<NLAYER, 128, 0, stream>>>(Wee, bee, We, be, weff);

    int tiles32 = (N_NODES + 31)/32;
    qkvs_mfma_kernel<<<dim3(tiles32, 2), 256, 0, stream>>>(hb, wqkvsT,
        bq, bk, bv, bs, qs, kv);
    for (int l = 0; l < NLAYER; ++l){
        attn_kernel<<<(N_NODES+3)/4, 256, 0, stream>>>(qs, kv,
            weff + (size_t)l*8*DIM, rowptr, srcs, eab, h,
            n1g + (size_t)l*DIM, n1b + (size_t)l*DIM, x1b);
        int has = (l < NLAYER-1);
        ffn_qkvs_kernel<<<tiles32, 256, 0, stream>>>(x1b, h,
            w1T + (size_t)l*32768, b1 + (size_t)l*2*DIM,
            w2T + (size_t)l*32768, b2 + (size_t)l*DIM,
            n2g + (size_t)l*DIM, n2b + (size_t)l*DIM,
            lng + (size_t)l*DIM, lnb + (size_t)l*DIM,
            has, h,
            has, wqkvsT + (size_t)(l+1 < NLAYER ? l+1 : 0)*65536,
            bq + (size_t)(l+1 < NLAYER ? l+1 : 0)*DIM,
            bk + (size_t)(l+1 < NLAYER ? l+1 : 0)*DIM,
            bv + (size_t)(l+1 < NLAYER ? l+1 : 0)*DIM,
            bs + (size_t)(l+1 < NLAYER ? l+1 : 0)*DIM,
            qs, kv);
    }
}